// Round 4
// baseline (916.109 us; speedup 1.0000x reference)
//
#include <hip/hip_runtime.h>

#define NPTS 300000
#define LOG2T 19
#define TSIZE (1u<<LOG2T)
#define NROWS 300032u          // = 1172 * 256
#define BLKS_PER_LV 1172u

typedef float f32x4 __attribute__((ext_vector_type(4)));
typedef __bf16 bf16x8 __attribute__((ext_vector_type(8)));

__device__ __forceinline__ unsigned short f2bf(float f){
  unsigned u = __builtin_bit_cast(unsigned, f);
  u += 0x7fffu + ((u>>16)&1u);          // round-to-nearest-even
  return (unsigned short)(u>>16);
}

// swizzled byte offset within a 32x64 bf16 (4KB) per-wave buffer (128B rows)
__device__ __forceinline__ int swz(int row, int bytecol){
  return (row*128 + bytecol) ^ ((row & 7) << 4);
}

// ---------------- prep: weights f32->bf16 B-frags + table f32->packed bf16 ---
struct WP { const float* p[17]; };

__device__ const int LK[17]  = {32,64, 64,64,64, 64,64,64, 64,64,64, 64,64,64, 64,64,64};
__device__ const int LN[17]  = {64,64, 64,64, 3, 64,64, 3, 64,64, 4, 64,64, 1, 64,64,48};
__device__ const int LNT[17] = { 4, 4,  4, 4, 1,  4, 4, 1,  4, 4, 1,  4, 4, 1,  4, 4, 3};
__device__ const int LOFF[17]= {0,4096, 12288,20480,28672, 30720,38912,47104,
                                49152,57344,65536, 67584,75776,83968, 86016,94208,102400};

__global__ void prep_all(WP wp, unsigned short* wdst,
                         const float* __restrict__ t, unsigned* __restrict__ tdst){
  int gtid = blockIdx.x*blockDim.x + threadIdx.x;
  int gstr = blockDim.x*gridDim.x;
  if(tdst){
    int n = (16 << LOG2T) / 2;  // 4M float4 -> uint2
    for(int i=gtid; i<n; i+=gstr){
      float4 f = ((const float4*)t)[i];
      uint2 o;
      o.x = (unsigned)f2bf(f.x) | ((unsigned)f2bf(f.y)<<16);
      o.y = (unsigned)f2bf(f.z) | ((unsigned)f2bf(f.w)<<16);
      ((uint2*)tdst)[i] = o;
    }
  }
  for(int layer=0; layer<17; layer++){
    const float* W = wp.p[layer];
    int K = LK[layer], Nn = LN[layer], NT = LNT[layer];
    unsigned short* d = wdst + LOFF[layer]/2;
    int nel = (K/32) * NT * 512;
    for(int i=gtid; i<nel; i += gstr){
      int j = i & 7, l = (i>>3)&63, fidx = i>>9;
      int kt = fidx / NT, nt = fidx - kt*NT;
      int k = kt*32 + ((l>>4)<<3) + j;
      int n = nt*16 + (l&15);
      unsigned short v = 0;
      if(n < Nn) v = f2bf(W[k*Nn + n]);
      d[i] = v;
    }
  }
}

// ---------------- encode: one thread per (point, level), level-major blocks --
template<bool BT>
__global__ __launch_bounds__(256) void encode_lv(
    const float* __restrict__ xyz, const float* __restrict__ timep,
    const float* __restrict__ bmin, const float* __restrict__ bmax,
    const void* __restrict__ tab, unsigned* __restrict__ enc_t)
{
  unsigned bid = blockIdx.x;
  unsigned lv = bid / BLKS_PER_LV;
  unsigned p = (bid - lv*BLKS_PER_LV)*256u + threadIdx.x;
  size_t oidx = (size_t)lv*NROWS + p;
  if(p >= NPTS){ enc_t[oidx] = 0u; return; }

  float m0=bmin[0], m1=bmin[1], m2=bmin[2];
  float M0=bmax[0], M1=bmax[1], M2=bmax[2];
  float c0 = fminf(fmaxf((xyz[3*p  ]-m0)/(M0-m0),0.f),1.f);
  float c1 = fminf(fmaxf((xyz[3*p+1]-m1)/(M1-m1),0.f),1.f);
  float c2 = fminf(fmaxf((xyz[3*p+2]-m2)/(M2-m2),0.f),1.f);
  float c3 = fminf(fmaxf(timep[p],0.f),1.f);

  float sc = (float)(16<<lv) - 1.0f;
  float pos0 = c0*sc + 0.5f, pos1 = c1*sc + 0.5f;
  float pos2 = c2*sc + 0.5f, pos3 = c3*sc + 0.5f;
  float f0 = floorf(pos0), f1 = floorf(pos1), f2 = floorf(pos2), f3 = floorf(pos3);
  float w0 = pos0-f0, w1 = pos1-f1, w2 = pos2-f2, w3 = pos3-f3;
  unsigned i0 = (unsigned)f0, i1 = (unsigned)f1, i2 = (unsigned)f2, i3 = (unsigned)f3;
  unsigned hx0 = i0,                 hx1 = i0 + 1u;
  unsigned hy0 = i1*2654435761u,     hy1 = hy0 + 2654435761u;
  unsigned hz0 = i2*805459861u,      hz1 = hz0 + 805459861u;
  unsigned ht0 = i3*3674653429u,     ht1 = ht0 + 3674653429u;
  float u0=1.f-w0, u1=1.f-w1, u2=1.f-w2, u3=1.f-w3;
  float wxy[4] = {u0*u1, w0*u1, u0*w1, w0*w1};
  float wzt[4] = {u2*u3, w2*u3, u2*w3, w2*w3};
  float a0 = 0.f, a1 = 0.f;
  if(BT){
    const unsigned* tb = (const unsigned*)tab + ((size_t)lv<<LOG2T);
    unsigned v[16];
    #pragma unroll
    for(int cc=0;cc<16;cc++){
      unsigned h = ((cc&1)?hx1:hx0) ^ ((cc&2)?hy1:hy0) ^ ((cc&4)?hz1:hz0) ^ ((cc&8)?ht1:ht0);
      v[cc] = __builtin_nontemporal_load(tb + (h & (TSIZE-1u)));
    }
    #pragma unroll
    for(int cc=0;cc<16;cc++){
      float wc = wxy[cc&3]*wzt[cc>>2];
      float fx = __builtin_bit_cast(float, v[cc]<<16);
      float fy = __builtin_bit_cast(float, v[cc]&0xffff0000u);
      a0 = fmaf(fx, wc, a0);
      a1 = fmaf(fy, wc, a1);
    }
  } else {
    const float* tb = (const float*)tab + ((size_t)lv<<(LOG2T+1));
    float2 v[16];
    #pragma unroll
    for(int cc=0;cc<16;cc++){
      unsigned h = ((cc&1)?hx1:hx0) ^ ((cc&2)?hy1:hy0) ^ ((cc&4)?hz1:hz0) ^ ((cc&8)?ht1:ht0);
      const float* ep = tb + ((size_t)(h&(TSIZE-1u))<<1);
      v[cc].x = __builtin_nontemporal_load(ep);
      v[cc].y = __builtin_nontemporal_load(ep+1);
    }
    #pragma unroll
    for(int cc=0;cc<16;cc++){
      float wc = wxy[cc&3]*wzt[cc>>2];
      a0 = fmaf(v[cc].x, wc, a0);
      a1 = fmaf(v[cc].y, wc, a1);
    }
  }
  enc_t[oidx] = (unsigned)f2bf(a0) | ((unsigned)f2bf(a1)<<16);
}

// ---------------- MLP building blocks (M=32 per wave: 2 m-tiles) -------------
__device__ __forceinline__ void relu_store(f32x4 acc, char* bout, int mt, int nt,
                                           int q, int r){
  #pragma unroll
  for(int rr=0;rr<4;rr++){
    float v = fmaxf(acc[rr], 0.f);
    *(unsigned short*)(bout + swz(16*mt + 4*q + rr, 2*(r + 16*nt))) = f2bf(v);
  }
}

// layer 0: A from transposed enc (coalesced dword loads)
__device__ __forceinline__ void mlp_first(const unsigned* __restrict__ enc_t,
                                          int pb, char* bout, const char* wbase, int lane){
  const int q = lane>>4, r = lane&15;
  bf16x8 a[2];
  #pragma unroll
  for(int mt=0;mt<2;mt++){
    int prow = pb + r + 16*mt;
    uint4 t;
    t.x = enc_t[(size_t)(4*q+0)*NROWS + prow];
    t.y = enc_t[(size_t)(4*q+1)*NROWS + prow];
    t.z = enc_t[(size_t)(4*q+2)*NROWS + prow];
    t.w = enc_t[(size_t)(4*q+3)*NROWS + prow];
    a[mt] = __builtin_bit_cast(bf16x8, t);
  }
  const bf16x8* wf = (const bf16x8*)wbase;
  f32x4 acc[2][4];
  #pragma unroll
  for(int mt=0;mt<2;mt++)
    #pragma unroll
    for(int nt=0;nt<4;nt++)
      acc[mt][nt] = f32x4{0.f,0.f,0.f,0.f};
  #pragma unroll
  for(int nt=0;nt<4;nt++){
    bf16x8 b = wf[nt*64 + lane];
    #pragma unroll
    for(int mt=0;mt<2;mt++)
      acc[mt][nt] = __builtin_amdgcn_mfma_f32_16x16x32_bf16(a[mt], b, acc[mt][nt], 0,0,0);
  }
  #pragma unroll
  for(int mt=0;mt<2;mt++)
    #pragma unroll
    for(int nt=0;nt<4;nt++)
      relu_store(acc[mt][nt], bout, mt, nt, q, r);
}

template<int KT, int NT>
__device__ __forceinline__ void mlp_hidden(const char* bin, char* bout,
                                           const char* wbase, int lane){
  const int q = lane>>4, r = lane&15;
  bf16x8 a[2][KT];
  #pragma unroll
  for(int kt=0;kt<KT;kt++)
    #pragma unroll
    for(int mt=0;mt<2;mt++)
      a[mt][kt] = *(const bf16x8*)(bin + swz(r + 16*mt, kt*64 + q*16));
  const bf16x8* wf = (const bf16x8*)wbase;
  bf16x8 b[NT][KT];
  #pragma unroll
  for(int kt=0;kt<KT;kt++)
    #pragma unroll
    for(int nt=0;nt<NT;nt++)
      b[nt][kt] = wf[(kt*NT+nt)*64 + lane];
  f32x4 acc[2][NT];
  #pragma unroll
  for(int mt=0;mt<2;mt++)
    #pragma unroll
    for(int nt=0;nt<NT;nt++)
      acc[mt][nt] = f32x4{0.f,0.f,0.f,0.f};
  #pragma unroll
  for(int kt=0;kt<KT;kt++)
    #pragma unroll
    for(int mt=0;mt<2;mt++)
      #pragma unroll
      for(int nt=0;nt<NT;nt++)
        acc[mt][nt] = __builtin_amdgcn_mfma_f32_16x16x32_bf16(a[mt][kt], b[nt][kt], acc[mt][nt], 0,0,0);
  #pragma unroll
  for(int mt=0;mt<2;mt++)
    #pragma unroll
    for(int nt=0;nt<NT;nt++)
      relu_store(acc[mt][nt], bout, mt, nt, q, r);
}

template<int NT>
__device__ __forceinline__ void mlp_final(const char* bin, const char* wbase,
                                          int lane, f32x4 (&acc)[2][NT]){
  const int q = lane>>4, r = lane&15;
  bf16x8 a[2][2];
  #pragma unroll
  for(int kt=0;kt<2;kt++)
    #pragma unroll
    for(int mt=0;mt<2;mt++)
      a[mt][kt] = *(const bf16x8*)(bin + swz(r + 16*mt, kt*64 + q*16));
  const bf16x8* wf = (const bf16x8*)wbase;
  #pragma unroll
  for(int mt=0;mt<2;mt++)
    #pragma unroll
    for(int nt=0;nt<NT;nt++)
      acc[mt][nt] = f32x4{0.f,0.f,0.f,0.f};
  #pragma unroll
  for(int kt=0;kt<2;kt++)
    #pragma unroll
    for(int nt=0;nt<NT;nt++){
      bf16x8 b = wf[(kt*NT+nt)*64 + lane];
      #pragma unroll
      for(int mt=0;mt<2;mt++)
        acc[mt][nt] = __builtin_amdgcn_mfma_f32_16x16x32_bf16(a[mt][kt], b, acc[mt][nt], 0,0,0);
    }
}

template<int NT>
__device__ __forceinline__ void head_store(f32x4 (&acc)[2][NT], const float* resid,
    float* outp, int od, int pb, int lane, unsigned long long bal){
  const int q = lane>>4, r = lane&15;
  #pragma unroll
  for(int mt=0;mt<2;mt++)
    #pragma unroll
    for(int rr=0;rr<4;rr++){
      int prow = 16*mt + 4*q + rr;
      int p = pb + prow;
      if(p >= NPTS) continue;
      float m = ((bal>>prow)&1ull) ? 1.f : 0.f;
      #pragma unroll
      for(int nt=0;nt<NT;nt++){
        int n = r + 16*nt;
        if(n < od){
          size_t idx = (size_t)p*od + n;
          outp[idx] = resid[idx] + m*acc[mt][nt][rr];
        }
      }
    }
}

// ---------------- MLP kernel: 1 wave/block, 32 points per wave ---------------
__global__ __launch_bounds__(64,4) void mlp_k(
    const float* __restrict__ xyz, const float* __restrict__ scales,
    const float* __restrict__ rots, const float* __restrict__ opac,
    const float* __restrict__ shs,
    const float* __restrict__ bmin, const float* __restrict__ bmax,
    const unsigned* __restrict__ enc_t, const unsigned short* __restrict__ wsw,
    float* __restrict__ out)
{
  __shared__ __align__(16) char lds[2][4096];
  const int lane = threadIdx.x;
  const int pb = blockIdx.x*32;
  char* b0 = &lds[0][0];
  char* b1 = &lds[1][0];

  bool mkb = false;
  if(lane < 32){
    int p = pb + lane;
    if(p < NPTS){
      float m0=bmin[0], m1=bmin[1], m2=bmin[2];
      float M0=bmax[0], M1=bmax[1], M2=bmax[2];
      float c0 = (xyz[3*p  ]-m0)/(M0-m0);
      float c1 = (xyz[3*p+1]-m1)/(M1-m1);
      float c2 = (xyz[3*p+2]-m2)/(M2-m2);
      mkb = (c0>=0.f && c0<=1.f && c1>=0.f && c1<=1.f && c2>=0.f && c2<=1.f);
    }
  }
  unsigned long long bal = __ballot(mkb);

  const char* wsb = (const char*)wsw;

  mlp_first(enc_t, pb, b1, wsb+0, lane);      // enc0: K=32, A from global
  mlp_hidden<2,4>(b1, b0, wsb+4096,  lane);   // enc1 -> shared hidden in b0

  f32x4 accs[2][1];
  f32x4 acc3[2][3];

  // xyz head
  mlp_hidden<2,4>(b0, b1, wsb+12288, lane);
  mlp_hidden<2,4>(b1, b1, wsb+20480, lane);
  mlp_final<1>(b1, wsb+28672, lane, accs);
  head_store<1>(accs, xyz, out, 3, pb, lane, bal);

  // scales head
  mlp_hidden<2,4>(b0, b1, wsb+30720, lane);
  mlp_hidden<2,4>(b1, b1, wsb+38912, lane);
  mlp_final<1>(b1, wsb+47104, lane, accs);
  head_store<1>(accs, scales, out + (size_t)3*NPTS, 3, pb, lane, bal);

  // rotations head
  mlp_hidden<2,4>(b0, b1, wsb+49152, lane);
  mlp_hidden<2,4>(b1, b1, wsb+57344, lane);
  mlp_final<1>(b1, wsb+65536, lane, accs);
  head_store<1>(accs, rots, out + (size_t)6*NPTS, 4, pb, lane, bal);

  // opacity head
  mlp_hidden<2,4>(b0, b1, wsb+67584, lane);
  mlp_hidden<2,4>(b1, b1, wsb+75776, lane);
  mlp_final<1>(b1, wsb+83968, lane, accs);
  head_store<1>(accs, opac, out + (size_t)10*NPTS, 1, pb, lane, bal);

  // shs head
  mlp_hidden<2,4>(b0, b1, wsb+86016, lane);
  mlp_hidden<2,4>(b1, b1, wsb+94208, lane);
  mlp_final<3>(b1, wsb+102400, lane, acc3);
  head_store<3>(acc3, shs, out + (size_t)11*NPTS, 48, pb, lane, bal);
}

extern "C" void kernel_launch(void* const* d_in, const int* in_sizes, int n_in,
                              void* d_out, int out_size, void* d_ws, size_t ws_size,
                              hipStream_t stream){
  (void)in_sizes; (void)n_in; (void)out_size;
  WP wp;
  for(int i=0;i<17;i++) wp.p[i] = (const float*)d_in[9+i];
  char* ws = (char*)d_ws;
  unsigned short* wsw = (unsigned short*)ws;

  const size_t TAB_OFF   = 131072;
  const size_t TAB_BYTES = (size_t)(16u<<LOG2T) * 4;   // 32 MB packed bf16
  const size_t ENC_BYTES = (size_t)16 * NROWS * 4;     // 19.2 MB transposed enc
  bool bf16tab = ws_size >= TAB_OFF + TAB_BYTES + ENC_BYTES;
  size_t enc_off = bf16tab ? (TAB_OFF + TAB_BYTES) : TAB_OFF;
  unsigned* encp = (unsigned*)(ws + enc_off);

  const float* table = (const float*)d_in[8];
  unsigned* tabp = bf16tab ? (unsigned*)(ws + TAB_OFF) : nullptr;

  prep_all<<<4160,256,0,stream>>>(wp, wsw, table, tabp);

  unsigned enc_blocks = 16u * BLKS_PER_LV;
  if(bf16tab){
    encode_lv<true><<<enc_blocks,256,0,stream>>>(
        (const float*)d_in[0], (const float*)d_in[5],
        (const float*)d_in[6], (const float*)d_in[7], tabp, encp);
  } else {
    encode_lv<false><<<enc_blocks,256,0,stream>>>(
        (const float*)d_in[0], (const float*)d_in[5],
        (const float*)d_in[6], (const float*)d_in[7], table, encp);
  }

  mlp_k<<<NROWS/32,64,0,stream>>>(
      (const float*)d_in[0], (const float*)d_in[1], (const float*)d_in[2],
      (const float*)d_in[3], (const float*)d_in[4],
      (const float*)d_in[6], (const float*)d_in[7],
      encp, wsw, (float*)d_out);
}

// Round 5
// 364.421 us; speedup vs baseline: 2.5139x; 2.5139x over previous
//
#include <hip/hip_runtime.h>

#define NPTS 300000
#define LOG2T 19
#define TSIZE (1u<<LOG2T)
#define NROWS 300032u          // = 1172 * 256
#define BLKS_PER_LV 1172u

typedef float f32x4 __attribute__((ext_vector_type(4)));
typedef __bf16 bf16x8 __attribute__((ext_vector_type(8)));

__device__ __forceinline__ unsigned short f2bf(float f){
  unsigned u = __builtin_bit_cast(unsigned, f);
  u += 0x7fffu + ((u>>16)&1u);          // round-to-nearest-even
  return (unsigned short)(u>>16);
}
__device__ __forceinline__ float bf_lo(unsigned v){ return __builtin_bit_cast(float, v<<16); }
__device__ __forceinline__ float bf_hi(unsigned v){ return __builtin_bit_cast(float, v&0xffff0000u); }

// swizzled byte offset within a 32x64 bf16 (4KB) per-wave buffer (128B rows)
__device__ __forceinline__ int swz(int row, int bytecol){
  return (row*128 + bytecol) ^ ((row & 7) << 4);
}

// ---------------- prep: weights f32->bf16 B-frags + table f32->packed bf16 ---
struct WP { const float* p[17]; };

__device__ const int LK[17]  = {32,64, 64,64,64, 64,64,64, 64,64,64, 64,64,64, 64,64,64};
__device__ const int LN[17]  = {64,64, 64,64, 3, 64,64, 3, 64,64, 4, 64,64, 1, 64,64,48};
__device__ const int LNT[17] = { 4, 4,  4, 4, 1,  4, 4, 1,  4, 4, 1,  4, 4, 1,  4, 4, 3};
__device__ const int LOFF[17]= {0,4096, 12288,20480,28672, 30720,38912,47104,
                                49152,57344,65536, 67584,75776,83968, 86016,94208,102400};

__global__ void prep_all(WP wp, unsigned short* wdst,
                         const float* __restrict__ t, unsigned* __restrict__ tdst){
  int gtid = blockIdx.x*blockDim.x + threadIdx.x;
  int gstr = blockDim.x*gridDim.x;
  if(tdst){
    int n = (16 << LOG2T) / 2;  // 4M float4 -> uint2
    for(int i=gtid; i<n; i+=gstr){
      float4 f = ((const float4*)t)[i];
      uint2 o;
      o.x = (unsigned)f2bf(f.x) | ((unsigned)f2bf(f.y)<<16);
      o.y = (unsigned)f2bf(f.z) | ((unsigned)f2bf(f.w)<<16);
      ((uint2*)tdst)[i] = o;
    }
  }
  for(int layer=0; layer<17; layer++){
    const float* W = wp.p[layer];
    int K = LK[layer], Nn = LN[layer], NT = LNT[layer];
    unsigned short* d = wdst + LOFF[layer]/2;
    int nel = (K/32) * NT * 512;
    for(int i=gtid; i<nel; i += gstr){
      int j = i & 7, l = (i>>3)&63, fidx = i>>9;
      int kt = fidx / NT, nt = fidx - kt*NT;
      int k = kt*32 + ((l>>4)<<3) + j;
      int n = nt*16 + (l&15);
      unsigned short v = 0;
      if(n < Nn) v = f2bf(W[k*Nn + n]);
      d[i] = v;
    }
  }
}

// ---------------- encode: one thread per (point, level), level-major blocks --
// x-pair trick: PRIMES[0]==1, so for even i0 the two x-corners are h and h^1
// -> one aligned uint2 gather serves both. Odd-i0 lanes fall back to a
// predicated scalar gather for the +x corner. ~12 line-requests instead of 16.
template<bool BT>
__global__ __launch_bounds__(256) void encode_lv(
    const float* __restrict__ xyz, const float* __restrict__ timep,
    const float* __restrict__ bmin, const float* __restrict__ bmax,
    const void* __restrict__ tab, unsigned* __restrict__ enc_t)
{
  unsigned bid = blockIdx.x;
  unsigned lv = bid / BLKS_PER_LV;
  unsigned p = (bid - lv*BLKS_PER_LV)*256u + threadIdx.x;
  size_t oidx = (size_t)lv*NROWS + p;
  if(p >= NPTS){ enc_t[oidx] = 0u; return; }

  float m0=bmin[0], m1=bmin[1], m2=bmin[2];
  float M0=bmax[0], M1=bmax[1], M2=bmax[2];
  float c0 = fminf(fmaxf((xyz[3*p  ]-m0)/(M0-m0),0.f),1.f);
  float c1 = fminf(fmaxf((xyz[3*p+1]-m1)/(M1-m1),0.f),1.f);
  float c2 = fminf(fmaxf((xyz[3*p+2]-m2)/(M2-m2),0.f),1.f);
  float c3 = fminf(fmaxf(timep[p],0.f),1.f);

  float sc = (float)(16<<lv) - 1.0f;
  float pos0 = c0*sc + 0.5f, pos1 = c1*sc + 0.5f;
  float pos2 = c2*sc + 0.5f, pos3 = c3*sc + 0.5f;
  float f0 = floorf(pos0), f1 = floorf(pos1), f2 = floorf(pos2), f3 = floorf(pos3);
  float w0 = pos0-f0, w1 = pos1-f1, w2 = pos2-f2, w3 = pos3-f3;
  unsigned i0 = (unsigned)f0, i1 = (unsigned)f1, i2 = (unsigned)f2, i3 = (unsigned)f3;
  unsigned hy0 = i1*2654435761u,     hy1 = hy0 + 2654435761u;
  unsigned hz0 = i2*805459861u,      hz1 = hz0 + 805459861u;
  unsigned ht0 = i3*3674653429u,     ht1 = ht0 + 3674653429u;
  float u0=1.f-w0, u1=1.f-w1, u2=1.f-w2, u3=1.f-w3;
  float a0 = 0.f, a1 = 0.f;
  if(BT){
    const unsigned* tb = (const unsigned*)tab + ((size_t)lv<<LOG2T);
    unsigned rh[8], va[8], vb[8];
    #pragma unroll
    for(int cc=0;cc<8;cc++){
      unsigned r = ((cc&1)?hy1:hy0) ^ ((cc&2)?hz1:hz0) ^ ((cc&4)?ht1:ht0);
      rh[cc] = r;
      unsigned h0 = (i0 ^ r) & (TSIZE-1u);
      uint2 v2 = *(const uint2*)(tb + (h0 & ~1u));
      va[cc] = (h0&1u)? v2.y : v2.x;
      vb[cc] = (h0&1u)? v2.x : v2.y;     // value at h0^1 == +x corner when i0 even
    }
    if(i0 & 1u){
      unsigned i0p = i0 + 1u;
      #pragma unroll
      for(int cc=0;cc<8;cc++)
        vb[cc] = tb[(i0p ^ rh[cc]) & (TSIZE-1u)];
    }
    float wyz[4] = {u1*u2, w1*u2, u1*w2, w1*w2};
    #pragma unroll
    for(int cc=0;cc<8;cc++){
      float wr = wyz[cc&3] * ((cc&4)? w3 : u3);
      float wa = u0*wr, wb = w0*wr;
      a0 = fmaf(bf_lo(va[cc]), wa, a0);
      a1 = fmaf(bf_hi(va[cc]), wa, a1);
      a0 = fmaf(bf_lo(vb[cc]), wb, a0);
      a1 = fmaf(bf_hi(vb[cc]), wb, a1);
    }
  } else {
    unsigned hx0 = i0, hx1 = i0 + 1u;
    float wxy[4] = {u0*u1, w0*u1, u0*w1, w0*w1};
    float wzt[4] = {u2*u3, w2*u3, u2*w3, w2*w3};
    const float* tb = (const float*)tab + ((size_t)lv<<(LOG2T+1));
    float2 v[16];
    #pragma unroll
    for(int cc=0;cc<16;cc++){
      unsigned h = ((cc&1)?hx1:hx0) ^ ((cc&2)?hy1:hy0) ^ ((cc&4)?hz1:hz0) ^ ((cc&8)?ht1:ht0);
      v[cc] = *(const float2*)(tb + ((size_t)(h&(TSIZE-1u))<<1));
    }
    #pragma unroll
    for(int cc=0;cc<16;cc++){
      float wc = wxy[cc&3]*wzt[cc>>2];
      a0 = fmaf(v[cc].x, wc, a0);
      a1 = fmaf(v[cc].y, wc, a1);
    }
  }
  enc_t[oidx] = (unsigned)f2bf(a0) | ((unsigned)f2bf(a1)<<16);
}

// ---------------- MLP building blocks (M=32 per wave: 2 m-tiles) -------------
__device__ __forceinline__ void relu_store(f32x4 acc, char* bout, int mt, int nt,
                                           int q, int r){
  #pragma unroll
  for(int rr=0;rr<4;rr++){
    float v = fmaxf(acc[rr], 0.f);
    *(unsigned short*)(bout + swz(16*mt + 4*q + rr, 2*(r + 16*nt))) = f2bf(v);
  }
}

// layer 0: A from transposed enc (coalesced dword loads)
__device__ __forceinline__ void mlp_first(const unsigned* __restrict__ enc_t,
                                          int pb, char* bout, const char* wbase, int lane){
  const int q = lane>>4, r = lane&15;
  bf16x8 a[2];
  #pragma unroll
  for(int mt=0;mt<2;mt++){
    int prow = pb + r + 16*mt;
    uint4 t;
    t.x = enc_t[(size_t)(4*q+0)*NROWS + prow];
    t.y = enc_t[(size_t)(4*q+1)*NROWS + prow];
    t.z = enc_t[(size_t)(4*q+2)*NROWS + prow];
    t.w = enc_t[(size_t)(4*q+3)*NROWS + prow];
    a[mt] = __builtin_bit_cast(bf16x8, t);
  }
  const bf16x8* wf = (const bf16x8*)wbase;
  f32x4 acc[2][4];
  #pragma unroll
  for(int mt=0;mt<2;mt++)
    #pragma unroll
    for(int nt=0;nt<4;nt++)
      acc[mt][nt] = f32x4{0.f,0.f,0.f,0.f};
  #pragma unroll
  for(int nt=0;nt<4;nt++){
    bf16x8 b = wf[nt*64 + lane];
    #pragma unroll
    for(int mt=0;mt<2;mt++)
      acc[mt][nt] = __builtin_amdgcn_mfma_f32_16x16x32_bf16(a[mt], b, acc[mt][nt], 0,0,0);
  }
  #pragma unroll
  for(int mt=0;mt<2;mt++)
    #pragma unroll
    for(int nt=0;nt<4;nt++)
      relu_store(acc[mt][nt], bout, mt, nt, q, r);
}

template<int KT, int NT>
__device__ __forceinline__ void mlp_hidden(const char* bin, char* bout,
                                           const char* wbase, int lane){
  const int q = lane>>4, r = lane&15;
  bf16x8 a[2][KT];
  #pragma unroll
  for(int kt=0;kt<KT;kt++)
    #pragma unroll
    for(int mt=0;mt<2;mt++)
      a[mt][kt] = *(const bf16x8*)(bin + swz(r + 16*mt, kt*64 + q*16));
  const bf16x8* wf = (const bf16x8*)wbase;
  bf16x8 b[NT][KT];
  #pragma unroll
  for(int kt=0;kt<KT;kt++)
    #pragma unroll
    for(int nt=0;nt<NT;nt++)
      b[nt][kt] = wf[(kt*NT+nt)*64 + lane];
  f32x4 acc[2][NT];
  #pragma unroll
  for(int mt=0;mt<2;mt++)
    #pragma unroll
    for(int nt=0;nt<NT;nt++)
      acc[mt][nt] = f32x4{0.f,0.f,0.f,0.f};
  #pragma unroll
  for(int kt=0;kt<KT;kt++)
    #pragma unroll
    for(int mt=0;mt<2;mt++)
      #pragma unroll
      for(int nt=0;nt<NT;nt++)
        acc[mt][nt] = __builtin_amdgcn_mfma_f32_16x16x32_bf16(a[mt][kt], b[nt][kt], acc[mt][nt], 0,0,0);
  #pragma unroll
  for(int mt=0;mt<2;mt++)
    #pragma unroll
    for(int nt=0;nt<NT;nt++)
      relu_store(acc[mt][nt], bout, mt, nt, q, r);
}

template<int NT>
__device__ __forceinline__ void mlp_final(const char* bin, const char* wbase,
                                          int lane, f32x4 (&acc)[2][NT]){
  const int q = lane>>4, r = lane&15;
  bf16x8 a[2][2];
  #pragma unroll
  for(int kt=0;kt<2;kt++)
    #pragma unroll
    for(int mt=0;mt<2;mt++)
      a[mt][kt] = *(const bf16x8*)(bin + swz(r + 16*mt, kt*64 + q*16));
  const bf16x8* wf = (const bf16x8*)wbase;
  #pragma unroll
  for(int mt=0;mt<2;mt++)
    #pragma unroll
    for(int nt=0;nt<NT;nt++)
      acc[mt][nt] = f32x4{0.f,0.f,0.f,0.f};
  #pragma unroll
  for(int kt=0;kt<2;kt++)
    #pragma unroll
    for(int nt=0;nt<NT;nt++){
      bf16x8 b = wf[(kt*NT+nt)*64 + lane];
      #pragma unroll
      for(int mt=0;mt<2;mt++)
        acc[mt][nt] = __builtin_amdgcn_mfma_f32_16x16x32_bf16(a[mt][kt], b, acc[mt][nt], 0,0,0);
    }
}

template<int NT>
__device__ __forceinline__ void head_store(f32x4 (&acc)[2][NT], const float* resid,
    float* outp, int od, int pb, int lane, const unsigned char* mk){
  const int q = lane>>4, r = lane&15;
  #pragma unroll
  for(int mt=0;mt<2;mt++)
    #pragma unroll
    for(int rr=0;rr<4;rr++){
      int prow = 16*mt + 4*q + rr;
      int p = pb + prow;
      if(p >= NPTS) continue;
      float m = mk[prow] ? 1.f : 0.f;
      #pragma unroll
      for(int nt=0;nt<NT;nt++){
        int n = r + 16*nt;
        if(n < od){
          size_t idx = (size_t)p*od + n;
          outp[idx] = resid[idx] + m*acc[mt][nt][rr];
        }
      }
    }
}

// ---------------- MLP kernel: 4 waves/block, 32 points per wave --------------
__global__ __launch_bounds__(256,4) void mlp_k(
    const float* __restrict__ xyz, const float* __restrict__ scales,
    const float* __restrict__ rots, const float* __restrict__ opac,
    const float* __restrict__ shs,
    const float* __restrict__ bmin, const float* __restrict__ bmax,
    const unsigned* __restrict__ enc_t, const unsigned short* __restrict__ wsw,
    float* __restrict__ out)
{
  __shared__ __align__(16) char lds[4][2][4096];
  __shared__ unsigned char mlds[4][32];
  const int w = threadIdx.x>>6, lane = threadIdx.x&63;
  const int pb = (blockIdx.x*4 + w)*32;
  char* b0 = &lds[w][0][0];
  char* b1 = &lds[w][1][0];

  if(lane < 32){
    int p = pb + lane;
    unsigned char mk = 0;
    if(p < NPTS){
      float m0=bmin[0], m1=bmin[1], m2=bmin[2];
      float M0=bmax[0], M1=bmax[1], M2=bmax[2];
      float c0 = (xyz[3*p  ]-m0)/(M0-m0);
      float c1 = (xyz[3*p+1]-m1)/(M1-m1);
      float c2 = (xyz[3*p+2]-m2)/(M2-m2);
      mk = (c0>=0.f && c0<=1.f && c1>=0.f && c1<=1.f && c2>=0.f && c2<=1.f) ? 1 : 0;
    }
    mlds[w][lane] = mk;
  }

  const char* wsb = (const char*)wsw;
  const unsigned char* mk = &mlds[w][0];

  mlp_first(enc_t, pb, b1, wsb+0, lane);      // enc0: K=32, A from global
  mlp_hidden<2,4>(b1, b0, wsb+4096,  lane);   // enc1 -> shared hidden in b0

  f32x4 accs[2][1];
  f32x4 acc3[2][3];

  // xyz head
  mlp_hidden<2,4>(b0, b1, wsb+12288, lane);
  mlp_hidden<2,4>(b1, b1, wsb+20480, lane);
  mlp_final<1>(b1, wsb+28672, lane, accs);
  head_store<1>(accs, xyz, out, 3, pb, lane, mk);

  // scales head
  mlp_hidden<2,4>(b0, b1, wsb+30720, lane);
  mlp_hidden<2,4>(b1, b1, wsb+38912, lane);
  mlp_final<1>(b1, wsb+47104, lane, accs);
  head_store<1>(accs, scales, out + (size_t)3*NPTS, 3, pb, lane, mk);

  // rotations head
  mlp_hidden<2,4>(b0, b1, wsb+49152, lane);
  mlp_hidden<2,4>(b1, b1, wsb+57344, lane);
  mlp_final<1>(b1, wsb+65536, lane, accs);
  head_store<1>(accs, rots, out + (size_t)6*NPTS, 4, pb, lane, mk);

  // opacity head
  mlp_hidden<2,4>(b0, b1, wsb+67584, lane);
  mlp_hidden<2,4>(b1, b1, wsb+75776, lane);
  mlp_final<1>(b1, wsb+83968, lane, accs);
  head_store<1>(accs, opac, out + (size_t)10*NPTS, 1, pb, lane, mk);

  // shs head
  mlp_hidden<2,4>(b0, b1, wsb+86016, lane);
  mlp_hidden<2,4>(b1, b1, wsb+94208, lane);
  mlp_final<3>(b1, wsb+102400, lane, acc3);
  head_store<3>(acc3, shs, out + (size_t)11*NPTS, 48, pb, lane, mk);
}

extern "C" void kernel_launch(void* const* d_in, const int* in_sizes, int n_in,
                              void* d_out, int out_size, void* d_ws, size_t ws_size,
                              hipStream_t stream){
  (void)in_sizes; (void)n_in; (void)out_size;
  WP wp;
  for(int i=0;i<17;i++) wp.p[i] = (const float*)d_in[9+i];
  char* ws = (char*)d_ws;
  unsigned short* wsw = (unsigned short*)ws;

  const size_t TAB_OFF   = 131072;
  const size_t TAB_BYTES = (size_t)(16u<<LOG2T) * 4;   // 32 MB packed bf16
  const size_t ENC_BYTES = (size_t)16 * NROWS * 4;     // 19.2 MB transposed enc
  bool bf16tab = ws_size >= TAB_OFF + TAB_BYTES + ENC_BYTES;
  size_t enc_off = bf16tab ? (TAB_OFF + TAB_BYTES) : TAB_OFF;
  unsigned* encp = (unsigned*)(ws + enc_off);

  const float* table = (const float*)d_in[8];
  unsigned* tabp = bf16tab ? (unsigned*)(ws + TAB_OFF) : nullptr;

  prep_all<<<4160,256,0,stream>>>(wp, wsw, table, tabp);

  unsigned enc_blocks = 16u * BLKS_PER_LV;
  if(bf16tab){
    encode_lv<true><<<enc_blocks,256,0,stream>>>(
        (const float*)d_in[0], (const float*)d_in[5],
        (const float*)d_in[6], (const float*)d_in[7], tabp, encp);
  } else {
    encode_lv<false><<<enc_blocks,256,0,stream>>>(
        (const float*)d_in[0], (const float*)d_in[5],
        (const float*)d_in[6], (const float*)d_in[7], table, encp);
  }

  mlp_k<<<NROWS/128,256,0,stream>>>(
      (const float*)d_in[0], (const float*)d_in[1], (const float*)d_in[2],
      (const float*)d_in[3], (const float*)d_in[4],
      (const float*)d_in[6], (const float*)d_in[7],
      encp, wsw, (float*)d_out);
}